// Round 1
// baseline (527.468 us; speedup 1.0000x reference)
//
#include <hip/hip_runtime.h>
#include <hip/hip_bf16.h>

// CrossAttn: out[b,n,d] = sum_m softmax_n(q k^T * scale)[n,m] * v[m,d]
// softmax over QUERY dim n  =>  out[n,d] = sum_m exp(s[n,m]) * v[m,d] / Z[m],
// Z[m] = sum_n exp(s[n,m]).  No max-subtraction needed (|s| <~ 24, fp32-safe).
//
// Pipeline (all bf16 MFMA, fp32 accum):
//   cvt fp32->bf16 (y,x,Wq,Wk,Wv)
//   q = y Wq^T + bq            [16384 x 512]   gemm_bt<EPI_BIAS>
//   k = x Wk^T + bk            [16384 x 512]
//   v = x Wv^T + bv            [16384 x 1024]
//   P = exp(q k^T * scale), Z[m] += colsum     gemm_bt<EPI_EXP> (batched)
//   vt[d,m] = v[m,d] / Z[m]    (transpose+scale -> B^T layout for PV)
//   out = P vt^T               fp32            gemm_bt<EPI_OUT> (batched)

using bf16 = __bf16;
typedef __attribute__((ext_vector_type(8))) __bf16 bf16x8;
typedef __attribute__((ext_vector_type(4))) float f32x4;

#define GLB_AS __attribute__((address_space(1)))
#define LDS_AS __attribute__((address_space(3)))

__device__ __forceinline__ void gload_lds16(const void* g, void* l) {
  __builtin_amdgcn_global_load_lds((const GLB_AS uint32_t*)g,
                                   (LDS_AS uint32_t*)l, 16, 0, 0);
}

enum { EPI_BIAS = 0, EPI_EXP = 1, EPI_OUT = 2 };

// m97-structure GEMM: C[M,N] = A[M,K] * Bt[N,K]^T ; 128x128 tile, BK=32,
// 256 threads = 4 waves (2x2), each wave 64x64 = 4x4 frags of 16x16x32 MFMA.
template <int EPI>
__global__ __launch_bounds__(256) void gemm_bt(
    const bf16* __restrict__ A, const bf16* __restrict__ Bt,
    void* __restrict__ Cv, const float* __restrict__ bias,
    float* __restrict__ Z, int M, int N, int K,
    long sA, long sB, long sC, float scale) {
  __shared__ __align__(16) bf16 As[128 * 32];
  __shared__ __align__(16) bf16 Bs[128 * 32];

  const int bz = blockIdx.z;
  const bf16* Ab = A + (long)bz * sA;
  const bf16* Bb = Bt + (long)bz * sB;

  const int tid = threadIdx.x;
  const int lane = tid & 63;
  const int wave = tid >> 6;
  const long m0 = (long)blockIdx.x * 128;
  const long n0 = (long)blockIdx.y * 128;
  const int wm = (wave >> 1) * 64;  // wave's row offset in tile
  const int wn = (wave & 1) * 64;   // wave's col offset in tile
  const int fl = lane & 15;         // frag row/col within 16
  const int kg = lane >> 4;         // k-group 0..3

  f32x4 acc[4][4] = {};

  // staging: thread t handles 16B chunk t (+256): row = t>>2, kchunk = t&3
  const int srow = tid >> 2;
  const int scol = (tid & 3) * 8;
  const bf16* gA = Ab + (m0 + srow) * (long)K + scol;
  const bf16* gB = Bb + (n0 + srow) * (long)K + scol;
  bf16* lA = As + tid * 8;
  bf16* lB = Bs + tid * 8;

  for (int k0 = 0; k0 < K; k0 += 32) {
    __syncthreads();  // previous compute done before overwriting LDS
    gload_lds16(gA, lA);
    gload_lds16(gA + 64L * K, lA + 2048);
    gload_lds16(gB, lB);
    gload_lds16(gB + 64L * K, lB + 2048);
    gA += 32;
    gB += 32;
    __syncthreads();  // staging visible (compiler drains vmcnt before barrier)

    bf16x8 a[4], b[4];
#pragma unroll
    for (int i = 0; i < 4; i++)
      a[i] = *(const bf16x8*)&As[(wm + i * 16 + fl) * 32 + kg * 8];
#pragma unroll
    for (int i = 0; i < 4; i++)
      b[i] = *(const bf16x8*)&Bs[(wn + i * 16 + fl) * 32 + kg * 8];
#pragma unroll
    for (int i = 0; i < 4; i++)
#pragma unroll
      for (int j = 0; j < 4; j++)
        acc[i][j] = __builtin_amdgcn_mfma_f32_16x16x32_bf16(a[i], b[j],
                                                            acc[i][j], 0, 0, 0);
  }

  // C/D frag mapping (verified m89/m91): col = lane&15, row = (lane>>4)*4 + r
  if constexpr (EPI == EPI_BIAS) {
    bf16* Cb = (bf16*)Cv + (long)bz * sC;
#pragma unroll
    for (int j = 0; j < 4; j++) {
      const long c = n0 + wn + j * 16 + fl;
      const float bc = bias[c];
#pragma unroll
      for (int i = 0; i < 4; i++)
#pragma unroll
        for (int r = 0; r < 4; r++) {
          const long rr = m0 + wm + i * 16 + kg * 4 + r;
          Cb[rr * N + c] = (bf16)(acc[i][j][r] + bc);
        }
    }
  } else if constexpr (EPI == EPI_EXP) {
    bf16* Cb = (bf16*)Cv + (long)bz * sC;
    float* Zb = Z + (long)bz * N;
#pragma unroll
    for (int j = 0; j < 4; j++) {
      const long c = n0 + wn + j * 16 + fl;
      float s = 0.f;
#pragma unroll
      for (int i = 0; i < 4; i++)
#pragma unroll
        for (int r = 0; r < 4; r++) {
          const long rr = m0 + wm + i * 16 + kg * 4 + r;
          const float e = __expf(acc[i][j][r] * scale);
          s += e;
          Cb[rr * N + c] = (bf16)e;
        }
      atomicAdd(&Zb[c], s);  // column sum over n (rows)
    }
  } else {  // EPI_OUT: plain fp32
    float* Cb = (float*)Cv + (long)bz * sC;
#pragma unroll
    for (int j = 0; j < 4; j++) {
      const long c = n0 + wn + j * 16 + fl;
#pragma unroll
      for (int i = 0; i < 4; i++)
#pragma unroll
        for (int r = 0; r < 4; r++) {
          const long rr = m0 + wm + i * 16 + kg * 4 + r;
          Cb[rr * N + c] = acc[i][j][r];
        }
    }
  }
}

__global__ void cvt_f32_bf16(const float* __restrict__ in,
                             bf16* __restrict__ out, long n4) {
  long i = blockIdx.x * (long)blockDim.x + threadIdx.x;
  const long stride = (long)gridDim.x * blockDim.x;
  for (; i < n4; i += stride) {
    const float4 f = ((const float4*)in)[i];
    union { ushort4 u; bf16 h[4]; } p;
    p.h[0] = (bf16)f.x;
    p.h[1] = (bf16)f.y;
    p.h[2] = (bf16)f.z;
    p.h[3] = (bf16)f.w;
    ((ushort4*)out)[i] = p.u;
  }
}

// vt[b][d][m] = v[b][m][d] / Z[b][m]  (32x32 LDS tile transpose, +1 pad)
__global__ __launch_bounds__(256) void transpose_scale(
    const bf16* __restrict__ v, const float* __restrict__ Z,
    bf16* __restrict__ vt) {
  __shared__ bf16 tile[32][33];
  const int b = blockIdx.z;
  const bf16* vb = v + (long)b * 2048 * 1024;
  bf16* vtb = vt + (long)b * 1024 * 2048;
  const float* Zb = Z + b * 2048;
  const int m0 = blockIdx.x * 32, d0 = blockIdx.y * 32;
  const int t = threadIdx.x;
  const int r = t >> 3, c4 = (t & 7) * 4;

  union { ushort4 u; bf16 h[4]; } in;
  in.u = *(const ushort4*)&vb[(long)(m0 + r) * 1024 + d0 + c4];
  tile[r][c4 + 0] = in.h[0];
  tile[r][c4 + 1] = in.h[1];
  tile[r][c4 + 2] = in.h[2];
  tile[r][c4 + 3] = in.h[3];
  __syncthreads();

  union { ushort4 u; bf16 h[4]; } o;
#pragma unroll
  for (int j = 0; j < 4; j++) {
    const float val = (float)tile[c4 + j][r] / Zb[m0 + c4 + j];
    o.h[j] = (bf16)val;
  }
  *(ushort4*)&vtb[(long)(d0 + r) * 2048 + m0 + c4] = o.u;
}

extern "C" void kernel_launch(void* const* d_in, const int* in_sizes, int n_in,
                              void* d_out, int out_size, void* d_ws,
                              size_t ws_size, hipStream_t stream) {
  const float* y = (const float*)d_in[0];   // [8,2048,1024]
  const float* x = (const float*)d_in[1];   // [8,2048,1024]
  const float* Wq = (const float*)d_in[2];  // [512,1024]
  const float* bq = (const float*)d_in[3];
  const float* Wk = (const float*)d_in[4];  // [512,1024]
  const float* bk = (const float*)d_in[5];
  const float* Wv = (const float*)d_in[6];  // [1024,1024]
  const float* bv = (const float*)d_in[7];
  float* out = (float*)d_out;

  constexpr long B = 8, Nq = 2048, Nk = 2048, Cd = 1024, CH = 512;
  constexpr long BNq = B * Nq;  // 16384
  const float scale = 0.04419417382415922f;  // 512^-0.5

  char* w = (char*)d_ws;
  auto alloc = [&](size_t bytes) {
    char* p = w;
    w += (bytes + 255) & ~(size_t)255;
    return p;
  };
  bf16* y_bf = (bf16*)alloc(BNq * Cd * 2);        // 33.5 MB
  bf16* x_bf = (bf16*)alloc(BNq * Cd * 2);        // 33.5 MB
  bf16* Wq_bf = (bf16*)alloc(CH * Cd * 2);
  bf16* Wk_bf = (bf16*)alloc(CH * Cd * 2);
  bf16* Wv_bf = (bf16*)alloc(Cd * Cd * 2);
  bf16* q_bf = (bf16*)alloc(BNq * CH * 2);        // 16.8 MB
  bf16* k_bf = (bf16*)alloc(BNq * CH * 2);        // 16.8 MB
  bf16* v_bf = (bf16*)alloc(BNq * Cd * 2);        // 33.5 MB
  bf16* vt_bf = (bf16*)alloc(BNq * Cd * 2);       // 33.5 MB
  bf16* P_bf = (bf16*)alloc(B * Nq * Nk * 2);     // 67 MB
  float* Zsum = (float*)alloc(B * Nk * 4);
  if ((size_t)(w - (char*)d_ws) > ws_size) return;  // ws too small -> loud fail

  // ---- fp32 -> bf16 conversions
  cvt_f32_bf16<<<2048, 256, 0, stream>>>(y, y_bf, BNq * Cd / 4);
  cvt_f32_bf16<<<2048, 256, 0, stream>>>(x, x_bf, BNq * Cd / 4);
  cvt_f32_bf16<<<512, 256, 0, stream>>>(Wq, Wq_bf, CH * Cd / 4);
  cvt_f32_bf16<<<512, 256, 0, stream>>>(Wk, Wk_bf, CH * Cd / 4);
  cvt_f32_bf16<<<1024, 256, 0, stream>>>(Wv, Wv_bf, Cd * Cd / 4);

  // ---- q, k, v projections (bias epilogue)
  gemm_bt<EPI_BIAS><<<dim3(128, 4, 1), 256, 0, stream>>>(
      y_bf, Wq_bf, q_bf, bq, nullptr, BNq, CH, Cd, 0, 0, 0, 0.f);
  gemm_bt<EPI_BIAS><<<dim3(128, 4, 1), 256, 0, stream>>>(
      x_bf, Wk_bf, k_bf, bk, nullptr, BNq, CH, Cd, 0, 0, 0, 0.f);
  gemm_bt<EPI_BIAS><<<dim3(128, 8, 1), 256, 0, stream>>>(
      x_bf, Wv_bf, v_bf, bv, nullptr, BNq, Cd, Cd, 0, 0, 0, 0.f);

  // ---- P = exp(q k^T * scale), Z = column sums (over n)
  hipMemsetAsync(Zsum, 0, B * Nk * 4, stream);
  gemm_bt<EPI_EXP><<<dim3(16, 16, 8), 256, 0, stream>>>(
      q_bf, k_bf, P_bf, nullptr, Zsum, Nq, Nk, CH,
      Nq * CH, Nk * CH, Nq * Nk, scale);

  // ---- vt[d,m] = v[m,d] / Z[m]
  transpose_scale<<<dim3(64, 32, 8), 256, 0, stream>>>(v_bf, Zsum, vt_bf);

  // ---- out = P * vt^T  (fp32)
  gemm_bt<EPI_OUT><<<dim3(16, 8, 8), 256, 0, stream>>>(
      P_bf, vt_bf, out, nullptr, nullptr, Nq, Cd, Nk,
      Nq * Nk, Cd * Nk, Nq * Cd, 0.f);
}

// Round 3
// 478.986 us; speedup vs baseline: 1.1012x; 1.1012x over previous
//
#include <hip/hip_runtime.h>
#include <hip/hip_bf16.h>

// CrossAttn: softmax over QUERY dim n =>
//   out[n,d] = sum_m exp(s[n,m]) * v[m,d] / Z[m],  Z[m] = sum_n exp(s[n,m]).
// Pipeline (bf16 MFMA, fp32 accum):
//   cvt fp32->bf16 (y, x, Wq, Wkv concat)
//   q  = y Wq^T  + bq              [16384 x 512]
//   kv = x Wkv^T + bkv             [16384 x 1536]  (k | v fused)
//   P = exp(q k^T * scale), Z[m] += colsum         (batched)
//   vt[d,m] = v[m,d] / Z[m]
//   out = P vt^T (fp32)                            (batched)
// GEMM: 256x256 tile, BK=32, 512 thr / 8 waves (2Mx4N), ring-of-4 LDS
// tile buffers, 2 phases/tile, counted vmcnt(8) (tiles t+2,t+3 in flight),
// setprio around MFMA clusters.  Race ledger:
//   - stage tile t+3 -> slot (t+3)&3 == (t-1)&3, freed at end of iter t-1
//     (all waves passed that barrier before iter t issues) -> WAR safe.
//   - vmcnt(8)+barrier at end of iter t: newest 8 loads = tiles t+3,t+2
//     -> tile t+1 landed on ALL waves before anyone reads it.   -> RAW safe.

using bf16 = __bf16;
typedef __attribute__((ext_vector_type(8))) __bf16 bf16x8;
typedef __attribute__((ext_vector_type(4))) float f32x4;

#define GLB_AS __attribute__((address_space(1)))
#define LDS_AS __attribute__((address_space(3)))

__device__ __forceinline__ void gload_lds16(const void* g, void* l) {
  __builtin_amdgcn_global_load_lds((const GLB_AS uint32_t*)g,
                                   (LDS_AS uint32_t*)l, 16, 0, 0);
}

#define BAR() __builtin_amdgcn_s_barrier()
#define LGK0() asm volatile("s_waitcnt lgkmcnt(0)" ::: "memory")
#define VM8() asm volatile("s_waitcnt vmcnt(8)" ::: "memory")

enum { EPI_BIAS = 0, EPI_EXP = 1, EPI_OUT = 2 };

// C[M,N] = A[M,K] * Bt[N,K]^T.  M%256==0, N%256==0, K%32==0, K/32 >= 3.
template <int EPI>
__global__ __launch_bounds__(512, 2) void gemm256(
    const bf16* __restrict__ A, const bf16* __restrict__ Bt,
    void* __restrict__ Cv, const float* __restrict__ bias,
    float* __restrict__ Z, int M, int N, int K, int ldA, int ldB, int ldC,
    long sA, long sB, long sC, float scale) {
  __shared__ __align__(16) bf16 As[4 * 8192];  // 4 bufs x 256x32
  __shared__ __align__(16) bf16 Bs[4 * 8192];

  const int bz = blockIdx.z;
  const bf16* Ab = A + (long)bz * sA;
  const bf16* Bb = Bt + (long)bz * sB;

  const int tid = threadIdx.x;
  const int lane = tid & 63;
  const int wave = tid >> 6;
  const int wr = wave >> 2;  // 0..1 -> row offset wr*128
  const int wc = wave & 3;   // 0..3 -> col offset wc*64
  const int fl = lane & 15;
  const int kg = lane >> 4;
  const long m0 = (long)blockIdx.x * 256;
  const long n0 = (long)blockIdx.y * 256;

  f32x4 acc[8][4] = {};

  // staging: chunk c (of 1024 16B chunks per tile) -> row c>>2, col (c&3)*8.
  // thread handles chunks {tid, tid+512}; LDS dest byte = c*16 (linear,
  // wave-uniform base + lane*16 as global_load_lds requires).
  const int srow = tid >> 2;
  const int scol = (tid & 3) * 8;
  const bf16* gA0 = Ab + (m0 + srow) * (long)ldA + scol;
  const bf16* gA1 = Ab + (m0 + 128 + srow) * (long)ldA + scol;
  const bf16* gB0 = Bb + (n0 + srow) * (long)ldB + scol;
  const bf16* gB1 = Bb + (n0 + 128 + srow) * (long)ldB + scol;
  const int l0 = tid * 8, l1 = 4096 + tid * 8;

  const int nt = K >> 5;

#define STAGE_A(tt)                                    \
  {                                                    \
    const int _b = ((tt) & 3) * 8192;                  \
    const long _k = (long)(tt) * 32;                   \
    gload_lds16(gA0 + _k, &As[_b + l0]);               \
    gload_lds16(gA1 + _k, &As[_b + l1]);               \
  }
#define STAGE_B(tt)                                    \
  {                                                    \
    const int _b = ((tt) & 3) * 8192;                  \
    const long _k = (long)(tt) * 32;                   \
    gload_lds16(gB0 + _k, &Bs[_b + l0]);               \
    gload_lds16(gB1 + _k, &Bs[_b + l1]);               \
  }
#define RD_A(bo, i, mh) \
  (*(const bf16x8*)&As[(bo) + (wr * 128 + (mh)*64 + (i)*16 + fl) * 32 + kg * 8])
#define RD_B(bo, j) \
  (*(const bf16x8*)&Bs[(bo) + (wc * 64 + (j)*16 + fl) * 32 + kg * 8])

  // prologue: tiles 0,1,2 in flight (12 loads); tile0 landed after vmcnt(8).
  STAGE_A(0) STAGE_B(0) STAGE_A(1) STAGE_B(1) STAGE_A(2) STAGE_B(2)
  VM8();
  BAR();

  for (int t = 0; t < nt; ++t) {
    const int bo = (t & 3) * 8192;
    const int tt = t + 3;
    bf16x8 a0, a1, a2, a3, b0, b1, b2, b3;
    // ---- phase 0: m-frags 0..3, full B
    a0 = RD_A(bo, 0, 0); a1 = RD_A(bo, 1, 0);
    a2 = RD_A(bo, 2, 0); a3 = RD_A(bo, 3, 0);
    b0 = RD_B(bo, 0); b1 = RD_B(bo, 1); b2 = RD_B(bo, 2); b3 = RD_B(bo, 3);
    if (tt < nt) STAGE_A(tt);
    BAR();
    LGK0();
    __builtin_amdgcn_s_setprio(1);
#pragma unroll
    for (int j = 0; j < 4; j++) {
      acc[0][j] = __builtin_amdgcn_mfma_f32_16x16x32_bf16(a0, j == 0 ? b0 : j == 1 ? b1 : j == 2 ? b2 : b3, acc[0][j], 0, 0, 0);
      acc[1][j] = __builtin_amdgcn_mfma_f32_16x16x32_bf16(a1, j == 0 ? b0 : j == 1 ? b1 : j == 2 ? b2 : b3, acc[1][j], 0, 0, 0);
      acc[2][j] = __builtin_amdgcn_mfma_f32_16x16x32_bf16(a2, j == 0 ? b0 : j == 1 ? b1 : j == 2 ? b2 : b3, acc[2][j], 0, 0, 0);
      acc[3][j] = __builtin_amdgcn_mfma_f32_16x16x32_bf16(a3, j == 0 ? b0 : j == 1 ? b1 : j == 2 ? b2 : b3, acc[3][j], 0, 0, 0);
    }
    __builtin_amdgcn_s_setprio(0);
    BAR();
    // ---- phase 1: m-frags 4..7, reuse B regs
    a0 = RD_A(bo, 0, 1); a1 = RD_A(bo, 1, 1);
    a2 = RD_A(bo, 2, 1); a3 = RD_A(bo, 3, 1);
    if (tt < nt) STAGE_B(tt);
    BAR();
    LGK0();
    __builtin_amdgcn_s_setprio(1);
#pragma unroll
    for (int j = 0; j < 4; j++) {
      acc[4][j] = __builtin_amdgcn_mfma_f32_16x16x32_bf16(a0, j == 0 ? b0 : j == 1 ? b1 : j == 2 ? b2 : b3, acc[4][j], 0, 0, 0);
      acc[5][j] = __builtin_amdgcn_mfma_f32_16x16x32_bf16(a1, j == 0 ? b0 : j == 1 ? b1 : j == 2 ? b2 : b3, acc[5][j], 0, 0, 0);
      acc[6][j] = __builtin_amdgcn_mfma_f32_16x16x32_bf16(a2, j == 0 ? b0 : j == 1 ? b1 : j == 2 ? b2 : b3, acc[6][j], 0, 0, 0);
      acc[7][j] = __builtin_amdgcn_mfma_f32_16x16x32_bf16(a3, j == 0 ? b0 : j == 1 ? b1 : j == 2 ? b2 : b3, acc[7][j], 0, 0, 0);
    }
    __builtin_amdgcn_s_setprio(0);
    VM8();  // tile t+1 landed (t+2,t+3 may fly) -- counted, never 0
    BAR();
  }
#undef STAGE_A
#undef STAGE_B
#undef RD_A
#undef RD_B

  // C/D frag: col = lane&15, row = kg*4 + e (verified, round-1 passed)
  if constexpr (EPI == EPI_BIAS) {
    bf16* Cb = (bf16*)Cv + (long)bz * sC;
#pragma unroll
    for (int j = 0; j < 4; j++) {
      const long cc = n0 + wc * 64 + j * 16 + fl;
      const float bc = bias[cc];
#pragma unroll
      for (int mi = 0; mi < 8; mi++)
#pragma unroll
        for (int e = 0; e < 4; e++) {
          const long rr = m0 + wr * 128 + mi * 16 + kg * 4 + e;
          Cb[rr * ldC + cc] = (bf16)(acc[mi][j][e] + bc);
        }
    }
  } else if constexpr (EPI == EPI_EXP) {
    bf16* Cb = (bf16*)Cv + (long)bz * sC;
    float* Zb = Z + (long)bz * N;
#pragma unroll
    for (int j = 0; j < 4; j++) {
      const long cc = n0 + wc * 64 + j * 16 + fl;
      float zp = 0.f;
#pragma unroll
      for (int mi = 0; mi < 8; mi++)
#pragma unroll
        for (int e = 0; e < 4; e++) {
          const long rr = m0 + wr * 128 + mi * 16 + kg * 4 + e;
          const float ex = __expf(acc[mi][j][e] * scale);
          zp += ex;
          Cb[rr * ldC + cc] = (bf16)ex;
        }
      atomicAdd(&Zb[cc], zp);  // column sum over query rows n
    }
  } else {
    float* Cb = (float*)Cv + (long)bz * sC;
#pragma unroll
    for (int j = 0; j < 4; j++) {
      const long cc = n0 + wc * 64 + j * 16 + fl;
#pragma unroll
      for (int mi = 0; mi < 8; mi++)
#pragma unroll
        for (int e = 0; e < 4; e++) {
          const long rr = m0 + wr * 128 + mi * 16 + kg * 4 + e;
          Cb[rr * ldC + cc] = acc[mi][j][e];
        }
    }
  }
}

__global__ void cvt_f32_bf16(const float* __restrict__ in,
                             bf16* __restrict__ out, long n4) {
  long i = blockIdx.x * (long)blockDim.x + threadIdx.x;
  const long stride = (long)gridDim.x * blockDim.x;
  for (; i < n4; i += stride) {
    const float4 f = ((const float4*)in)[i];
    union { ushort4 u; bf16 h[4]; } p;
    p.h[0] = (bf16)f.x;
    p.h[1] = (bf16)f.y;
    p.h[2] = (bf16)f.z;
    p.h[3] = (bf16)f.w;
    ((ushort4*)out)[i] = p.u;
  }
}

// vt[b][d][m] = v[b][m][d] / Z[b][m]; v lives in kv (cols 512..1535, ld 1536)
__global__ __launch_bounds__(256) void transpose_scale(
    const bf16* __restrict__ kv, const float* __restrict__ Z,
    bf16* __restrict__ vt) {
  __shared__ bf16 tile[32][33];
  const int b = blockIdx.z;
  const bf16* vb = kv + (long)b * 2048 * 1536 + 512;
  bf16* vtb = vt + (long)b * 1024 * 2048;
  const float* Zb = Z + b * 2048;
  const int m0 = blockIdx.x * 32, d0 = blockIdx.y * 32;
  const int t = threadIdx.x;
  const int r = t >> 3, c4 = (t & 7) * 4;

  union { ushort4 u; bf16 h[4]; } in;
  in.u = *(const ushort4*)&vb[(long)(m0 + r) * 1536 + d0 + c4];
  tile[r][c4 + 0] = in.h[0];
  tile[r][c4 + 1] = in.h[1];
  tile[r][c4 + 2] = in.h[2];
  tile[r][c4 + 3] = in.h[3];
  __syncthreads();

  union { ushort4 u; bf16 h[4]; } o;
#pragma unroll
  for (int j = 0; j < 4; j++)
    o.h[j] = (bf16)((float)tile[c4 + j][r] / Zb[m0 + c4 + j]);
  *(ushort4*)&vtb[(long)(d0 + r) * 2048 + m0 + c4] = o.u;
}

extern "C" void kernel_launch(void* const* d_in, const int* in_sizes, int n_in,
                              void* d_out, int out_size, void* d_ws,
                              size_t ws_size, hipStream_t stream) {
  const float* y = (const float*)d_in[0];   // [8,2048,1024]
  const float* x = (const float*)d_in[1];   // [8,2048,1024]
  const float* Wq = (const float*)d_in[2];  // [512,1024]
  const float* bq = (const float*)d_in[3];
  const float* Wk = (const float*)d_in[4];  // [512,1024]
  const float* bk = (const float*)d_in[5];
  const float* Wv = (const float*)d_in[6];  // [1024,1024]
  const float* bv = (const float*)d_in[7];
  float* out = (float*)d_out;

  constexpr long B = 8, Nq = 2048, Nk = 2048, Cd = 1024, CH = 512;
  constexpr long BN = B * Nq;  // 16384
  const float scale = 0.04419417382415922f;  // 512^-0.5

  char* w = (char*)d_ws;
  auto alloc = [&](size_t bytes) {
    char* p = w;
    w += (bytes + 255) & ~(size_t)255;
    return p;
  };
  bf16* y_bf = (bf16*)alloc(BN * Cd * 2);          // 33.5 MB
  bf16* x_bf = (bf16*)alloc(BN * Cd * 2);          // 33.5 MB
  bf16* Wq_bf = (bf16*)alloc(CH * Cd * 2);         // 1 MB
  bf16* Wkv_bf = (bf16*)alloc((CH + Cd) * Cd * 2); // 3 MB (Wk | Wv rows)
  float* bkv = (float*)alloc((CH + Cd) * 4);
  bf16* q_bf = (bf16*)alloc(BN * CH * 2);          // 16.8 MB
  bf16* kv_bf = (bf16*)alloc(BN * (CH + Cd) * 2);  // 50.3 MB
  bf16* vt_bf = (bf16*)alloc(BN * Cd * 2);         // 33.5 MB
  bf16* P_bf = (bf16*)alloc(B * Nq * Nk * 2);      // 67 MB
  float* Zsum = (float*)alloc(B * Nk * 4);
  if ((size_t)(w - (char*)d_ws) > ws_size) return;

  // ---- fp32 -> bf16 (Wk,Wv concatenated into Wkv)
  cvt_f32_bf16<<<2048, 256, 0, stream>>>(y, y_bf, BN * Cd / 4);
  cvt_f32_bf16<<<2048, 256, 0, stream>>>(x, x_bf, BN * Cd / 4);
  cvt_f32_bf16<<<512, 256, 0, stream>>>(Wq, Wq_bf, CH * Cd / 4);
  cvt_f32_bf16<<<512, 256, 0, stream>>>(Wk, Wkv_bf, CH * Cd / 4);
  cvt_f32_bf16<<<1024, 256, 0, stream>>>(Wv, Wkv_bf + CH * Cd, Cd * Cd / 4);
  hipMemcpyAsync(bkv, bk, CH * 4, hipMemcpyDeviceToDevice, stream);
  hipMemcpyAsync(bkv + CH, bv, Cd * 4, hipMemcpyDeviceToDevice, stream);

  // ---- q = y Wq^T + bq ; kv = x Wkv^T + bkv
  gemm256<EPI_BIAS><<<dim3(64, 2, 1), 512, 0, stream>>>(
      y_bf, Wq_bf, q_bf, bq, nullptr, BN, CH, Cd, Cd, Cd, CH, 0, 0, 0, 0.f);
  gemm256<EPI_BIAS><<<dim3(64, 6, 1), 512, 0, stream>>>(
      x_bf, Wkv_bf, kv_bf, bkv, nullptr, BN, CH + Cd, Cd, Cd, Cd, CH + Cd,
      0, 0, 0, 0.f);

  // ---- P = exp(q k^T * scale), Z[m] = colsum over n
  hipMemsetAsync(Zsum, 0, B * Nk * 4, stream);
  gemm256<EPI_EXP><<<dim3(8, 8, 8), 512, 0, stream>>>(
      q_bf, kv_bf, P_bf, nullptr, Zsum, Nq, Nk, CH, CH, CH + Cd, Nk,
      Nq * CH, Nk * (CH + Cd), Nq * Nk, scale);

  // ---- vt[d,m] = v[m,d] / Z[m]
  transpose_scale<<<dim3(64, 32, 8), 256, 0, stream>>>(kv_bf, Zsum, vt_bf);

  // ---- out = P vt^T (fp32)
  gemm256<EPI_OUT><<<dim3(8, 4, 8), 512, 0, stream>>>(
      P_bf, vt_bf, out, nullptr, nullptr, Nq, Cd, Nk, Nk, Nk, Cd,
      Nq * Nk, Cd * Nk, Nq * Cd, 0.f);
}

// Round 4
// 471.979 us; speedup vs baseline: 1.1176x; 1.0148x over previous
//
#include <hip/hip_runtime.h>
#include <hip/hip_bf16.h>

// CrossAttn: softmax over QUERY dim n =>
//   out[n,d] = sum_m exp(s[n,m]) * v[m,d] / Z[m],  Z[m] = sum_n exp(s[n,m]).
// Pipeline (bf16 MFMA, fp32 accum):
//   cvt fp32->bf16; q = y Wq^T + bq; kv = x Wkv^T + bkv (k|v fused);
//   P = exp(q k^T * scale) with Z[m] colsum; vt[d,m] = v[m,d]/Z[m];
//   out = P vt^T (fp32).
//
// GEMM (m201-density port): 256x256 tile, BK=32, 512 thr / 8 waves (2Mx4N),
// per-wave 128x64 out. Ring-of-3 LDS slots (96 KiB). Per tile: 2 phases x
// {ds_read (10 or 2 b128) ; stage 2 gload_lds ; s_barrier ; lgkmcnt(0) ;
// setprio(1) ; 16 MFMA ; setprio(0) ; [vmcnt gate] ; s_barrier}.
//
// LDS swizzle (T2, 64B rows): logical byte l <-> slot s = l ^ (((l>>7)&7)<<4).
// Read: quad bits[6:4] = ((row&1)<<2|kg) ^ ((row>>1)&7) -> each 8-lane group
// spans all 8 bank quads (conflict-free). Write: gload_lds dest LINEAR
// (chunk c -> byte c*16); global source pre-swizzled: j = c ^ ((c>>3)&7),
// row=j>>2, col16=j&3 (coalescing kept: 8 threads cover one 128B row-slab).
//
// Race ledger (ring-3, stage 2 ahead):
//   WAR: tile t stages slot (t+2)%3 == slot (t-1)%3; all reads of t-1
//        retired before t-1's last lgkmcnt(0)+barrier -> safe.
//   RAW: end of tile t waits vmcnt(4) when t+2<nt (newest 4 = tile t+2's
//        loads; in-order retire => tile t+1 landed), else vmcnt(0)
//        (tail: nothing newer issued, counted wait can't prove t+1 landed).
//   Prologue: stage tiles 0,1 (8 loads), vmcnt(4) -> tile 0 landed.

using bf16 = __bf16;
typedef __attribute__((ext_vector_type(8))) __bf16 bf16x8;
typedef __attribute__((ext_vector_type(4))) float f32x4;

#define GLB_AS __attribute__((address_space(1)))
#define LDS_AS __attribute__((address_space(3)))

__device__ __forceinline__ void gload_lds16(const void* g, void* l) {
  __builtin_amdgcn_global_load_lds((const GLB_AS uint32_t*)g,
                                   (LDS_AS uint32_t*)l, 16, 0, 0);
}

#define BAR() __builtin_amdgcn_s_barrier()
#define LGK0() asm volatile("s_waitcnt lgkmcnt(0)" ::: "memory")
#define VM4() asm volatile("s_waitcnt vmcnt(4)" ::: "memory")
#define VM0() asm volatile("s_waitcnt vmcnt(0)" ::: "memory")

enum { EPI_BIAS = 0, EPI_EXP = 1, EPI_OUT = 2 };

// C[M,N] = A[M,K] * Bt[N,K]^T.  M%256==0, N%256==0, K%32==0, K/32 >= 3.
template <int EPI>
__global__ __launch_bounds__(512, 2) void gemm256(
    const bf16* __restrict__ A, const bf16* __restrict__ Bt,
    void* __restrict__ Cv, const float* __restrict__ bias,
    float* __restrict__ Z, int M, int N, int K, int ldA, int ldB, int ldC,
    long sA, long sB, long sC, float scale) {
  __shared__ __align__(16) bf16 As[3 * 8192];  // 3 slots x 256x32
  __shared__ __align__(16) bf16 Bs[3 * 8192];

  const int bz = blockIdx.z;
  const bf16* Ab = A + (long)bz * sA;
  const bf16* Bb = Bt + (long)bz * sB;

  const int tid = threadIdx.x;
  const int lane = tid & 63;
  const int wave = tid >> 6;
  const int wr = wave >> 2;  // 0..1: row offset wr*128
  const int wc = wave & 3;   // 0..3: col offset wc*64
  const int fl = lane & 15;
  const int kg = lane >> 4;
  const long m0 = (long)blockIdx.x * 256;
  const long n0 = (long)blockIdx.y * 256;

  f32x4 acc[8][4] = {};

  // ---- staging addressing (pre-swizzled global source, linear LDS dest)
  const int js = tid ^ ((tid >> 3) & 7);  // swizzled chunk -> logical block
  const int srow = js >> 2;               // 0..127
  const int scol = (js & 3) * 8;          // element col in the 32-wide slab
  const bf16* gAc = Ab + (m0 + srow) * (long)ldA + scol;
  const bf16* gBc = Bb + (n0 + srow) * (long)ldB + scol;
  char* Abase = (char*)As;
  char* Bbase = (char*)Bs;

#define STAGE_A(tt)                                         \
  {                                                         \
    char* _d = Abase + ((tt) % 3) * 16384 + tid * 16;       \
    const bf16* _g = gAc + (long)(tt) * 32;                 \
    gload_lds16(_g, _d);                                    \
    gload_lds16(_g + 128 * (long)ldA, _d + 8192);           \
  }
#define STAGE_B(tt)                                         \
  {                                                         \
    char* _d = Bbase + ((tt) % 3) * 16384 + tid * 16;       \
    const bf16* _g = gBc + (long)(tt) * 32;                 \
    gload_lds16(_g, _d);                                    \
    gload_lds16(_g + 128 * (long)ldB, _d + 8192);           \
  }

  // ---- swizzled read bases (per-thread constant)
  const int swz = (fl >> 1) << 4;
  const int abase = ((wr * 128 + fl) * 64 + kg * 16) ^ swz;
  const int bbase = ((wc * 64 + fl) * 64 + kg * 16) ^ swz;

  const int nt = K >> 5;

  // ---- prologue: tiles 0 and 1 staged; tile 0 guaranteed landed.
  STAGE_A(0) STAGE_B(0) STAGE_A(1) STAGE_B(1)
  VM4();
  BAR();

  for (int t = 0; t < nt; ++t) {
    const char* Asl = Abase + (t % 3) * 16384;
    const char* Bsl = Bbase + (t % 3) * 16384;
    bf16x8 a[8], b0, b1;
    // ======== phase 0: all 8 A-frags + B-frags 0,1 ========
#pragma unroll
    for (int mi = 0; mi < 8; mi++)
      a[mi] = *(const bf16x8*)(Asl + abase + mi * 1024);
    b0 = *(const bf16x8*)(Bsl + bbase);
    b1 = *(const bf16x8*)(Bsl + bbase + 1024);
    if (t + 2 < nt) STAGE_A(t + 2);
    BAR();
    LGK0();
    __builtin_amdgcn_s_setprio(1);
#pragma unroll
    for (int mi = 0; mi < 8; mi++) {
      acc[mi][0] = __builtin_amdgcn_mfma_f32_16x16x32_bf16(a[mi], b0, acc[mi][0], 0, 0, 0);
      acc[mi][1] = __builtin_amdgcn_mfma_f32_16x16x32_bf16(a[mi], b1, acc[mi][1], 0, 0, 0);
    }
    __builtin_amdgcn_s_setprio(0);
    BAR();
    // ======== phase 1: B-frags 2,3 (A reused) ========
    b0 = *(const bf16x8*)(Bsl + bbase + 2 * 1024);
    b1 = *(const bf16x8*)(Bsl + bbase + 3 * 1024);
    if (t + 2 < nt) STAGE_B(t + 2);
    BAR();
    LGK0();
    __builtin_amdgcn_s_setprio(1);
#pragma unroll
    for (int mi = 0; mi < 8; mi++) {
      acc[mi][2] = __builtin_amdgcn_mfma_f32_16x16x32_bf16(a[mi], b0, acc[mi][2], 0, 0, 0);
      acc[mi][3] = __builtin_amdgcn_mfma_f32_16x16x32_bf16(a[mi], b1, acc[mi][3], 0, 0, 0);
    }
    __builtin_amdgcn_s_setprio(0);
    if (t + 2 < nt) { VM4(); } else { VM0(); }  // counted; 0 only at tail
    BAR();
  }
#undef STAGE_A
#undef STAGE_B

  // ---- epilogue.  C/D frag: col = lane&15, row = kg*4 + e (verified R1/R3)
  if constexpr (EPI == EPI_BIAS) {
    bf16* Cb = (bf16*)Cv + (long)bz * sC;
#pragma unroll
    for (int j = 0; j < 4; j++) {
      const long cc = n0 + wc * 64 + j * 16 + fl;
      const float bc = bias[cc];
#pragma unroll
      for (int mi = 0; mi < 8; mi++)
#pragma unroll
        for (int e = 0; e < 4; e++) {
          const long rr = m0 + wr * 128 + mi * 16 + kg * 4 + e;
          Cb[rr * ldC + cc] = (bf16)(acc[mi][j][e] + bc);
        }
    }
  } else if constexpr (EPI == EPI_EXP) {
    bf16* Cb = (bf16*)Cv + (long)bz * sC;
    float* Zb = Z + (long)bz * N;
#pragma unroll
    for (int j = 0; j < 4; j++) {
      const long cc = n0 + wc * 64 + j * 16 + fl;
      float zp = 0.f;
#pragma unroll
      for (int mi = 0; mi < 8; mi++)
#pragma unroll
        for (int e = 0; e < 4; e++) {
          const long rr = m0 + wr * 128 + mi * 16 + kg * 4 + e;
          const float ex = __expf(acc[mi][j][e] * scale);
          zp += ex;
          Cb[rr * ldC + cc] = (bf16)ex;
        }
      atomicAdd(&Zb[cc], zp);  // column sum over query rows n
    }
  } else {
    float* Cb = (float*)Cv + (long)bz * sC;
#pragma unroll
    for (int j = 0; j < 4; j++) {
      const long cc = n0 + wc * 64 + j * 16 + fl;
#pragma unroll
      for (int mi = 0; mi < 8; mi++)
#pragma unroll
        for (int e = 0; e < 4; e++) {
          const long rr = m0 + wr * 128 + mi * 16 + kg * 4 + e;
          Cb[rr * ldC + cc] = acc[mi][j][e];
        }
    }
  }
}

__global__ void cvt_f32_bf16(const float* __restrict__ in,
                             bf16* __restrict__ out, long n4) {
  long i = blockIdx.x * (long)blockDim.x + threadIdx.x;
  const long stride = (long)gridDim.x * blockDim.x;
  for (; i < n4; i += stride) {
    const float4 f = ((const float4*)in)[i];
    union { ushort4 u; bf16 h[4]; } p;
    p.h[0] = (bf16)f.x;
    p.h[1] = (bf16)f.y;
    p.h[2] = (bf16)f.z;
    p.h[3] = (bf16)f.w;
    ((ushort4*)out)[i] = p.u;
  }
}

// vt[b][d][m] = v[b][m][d] / Z[b][m]; v lives in kv (cols 512..1535, ld 1536)
__global__ __launch_bounds__(256) void transpose_scale(
    const bf16* __restrict__ kv, const float* __restrict__ Z,
    bf16* __restrict__ vt) {
  __shared__ bf16 tile[32][33];
  const int b = blockIdx.z;
  const bf16* vb = kv + (long)b * 2048 * 1536 + 512;
  bf16* vtb = vt + (long)b * 1024 * 2048;
  const float* Zb = Z + b * 2048;
  const int m0 = blockIdx.x * 32, d0 = blockIdx.y * 32;
  const int t = threadIdx.x;
  const int r = t >> 3, c4 = (t & 7) * 4;

  union { ushort4 u; bf16 h[4]; } in;
  in.u = *(const ushort4*)&vb[(long)(m0 + r) * 1536 + d0 + c4];
  tile[r][c4 + 0] = in.h[0];
  tile[r][c4 + 1] = in.h[1];
  tile[r][c4 + 2] = in.h[2];
  tile[r][c4 + 3] = in.h[3];
  __syncthreads();

  union { ushort4 u; bf16 h[4]; } o;
#pragma unroll
  for (int j = 0; j < 4; j++)
    o.h[j] = (bf16)((float)tile[c4 + j][r] / Zb[m0 + c4 + j]);
  *(ushort4*)&vtb[(long)(d0 + r) * 2048 + m0 + c4] = o.u;
}

extern "C" void kernel_launch(void* const* d_in, const int* in_sizes, int n_in,
                              void* d_out, int out_size, void* d_ws,
                              size_t ws_size, hipStream_t stream) {
  const float* y = (const float*)d_in[0];   // [8,2048,1024]
  const float* x = (const float*)d_in[1];   // [8,2048,1024]
  const float* Wq = (const float*)d_in[2];  // [512,1024]
  const float* bq = (const float*)d_in[3];
  const float* Wk = (const float*)d_in[4];  // [512,1024]
  const float* bk = (const float*)d_in[5];
  const float* Wv = (const float*)d_in[6];  // [1024,1024]
  const float* bv = (const float*)d_in[7];
  float* out = (float*)d_out;

  constexpr long B = 8, Nq = 2048, Nk = 2048, Cd = 1024, CH = 512;
  constexpr long BN = B * Nq;  // 16384
  const float scale = 0.04419417382415922f;  // 512^-0.5

  char* w = (char*)d_ws;
  auto alloc = [&](size_t bytes) {
    char* p = w;
    w += (bytes + 255) & ~(size_t)255;
    return p;
  };
  bf16* y_bf = (bf16*)alloc(BN * Cd * 2);          // 33.5 MB
  bf16* x_bf = (bf16*)alloc(BN * Cd * 2);          // 33.5 MB
  bf16* Wq_bf = (bf16*)alloc(CH * Cd * 2);         // 1 MB
  bf16* Wkv_bf = (bf16*)alloc((CH + Cd) * Cd * 2); // 3 MB (Wk | Wv rows)
  float* bkv = (float*)alloc((CH + Cd) * 4);
  bf16* q_bf = (bf16*)alloc(BN * CH * 2);          // 16.8 MB
  bf16* kv_bf = (bf16*)alloc(BN * (CH + Cd) * 2);  // 50.3 MB
  bf16* vt_bf = (bf16*)alloc(BN * Cd * 2);         // 33.5 MB
  bf16* P_bf = (bf16*)alloc(B * Nq * Nk * 2);      // 67 MB
  float* Zsum = (float*)alloc(B * Nk * 4);
  if ((size_t)(w - (char*)d_ws) > ws_size) return;

  // ---- fp32 -> bf16 (Wk,Wv concatenated into Wkv)
  cvt_f32_bf16<<<2048, 256, 0, stream>>>(y, y_bf, BN * Cd / 4);
  cvt_f32_bf16<<<2048, 256, 0, stream>>>(x, x_bf, BN * Cd / 4);
  cvt_f32_bf16<<<512, 256, 0, stream>>>(Wq, Wq_bf, CH * Cd / 4);
  cvt_f32_bf16<<<512, 256, 0, stream>>>(Wk, Wkv_bf, CH * Cd / 4);
  cvt_f32_bf16<<<1024, 256, 0, stream>>>(Wv, Wkv_bf + CH * Cd, Cd * Cd / 4);
  hipMemcpyAsync(bkv, bk, CH * 4, hipMemcpyDeviceToDevice, stream);
  hipMemcpyAsync(bkv + CH, bv, Cd * 4, hipMemcpyDeviceToDevice, stream);

  // ---- q = y Wq^T + bq ; kv = x Wkv^T + bkv
  gemm256<EPI_BIAS><<<dim3(64, 2, 1), 512, 0, stream>>>(
      y_bf, Wq_bf, q_bf, bq, nullptr, BN, CH, Cd, Cd, Cd, CH, 0, 0, 0, 0.f);
  gemm256<EPI_BIAS><<<dim3(64, 6, 1), 512, 0, stream>>>(
      x_bf, Wkv_bf, kv_bf, bkv, nullptr, BN, CH + Cd, Cd, Cd, Cd, CH + Cd,
      0, 0, 0, 0.f);

  // ---- P = exp(q k^T * scale), Z[m] = colsum over n
  hipMemsetAsync(Zsum, 0, B * Nk * 4, stream);
  gemm256<EPI_EXP><<<dim3(8, 8, 8), 512, 0, stream>>>(
      q_bf, kv_bf, P_bf, nullptr, Zsum, Nq, Nk, CH, CH, CH + Cd, Nk,
      Nq * CH, Nk * (CH + Cd), Nq * Nk, scale);

  // ---- vt[d,m] = v[m,d] / Z[m]
  transpose_scale<<<dim3(64, 32, 8), 256, 0, stream>>>(kv_bf, Zsum, vt_bf);

  // ---- out = P vt^T (fp32)
  gemm256<EPI_OUT><<<dim3(8, 4, 8), 512, 0, stream>>>(
      P_bf, vt_bf, out, nullptr, nullptr, Nq, Cd, Nk, Nk, Nk, Cd,
      Nq * Nk, Cd * Nk, Nq * Cd, 0.f);
}